// Round 1
// baseline (805.300 us; speedup 1.0000x reference)
//
#include <hip/hip_runtime.h>

#define T_TOK 8192
#define HDIM  2048
#define NEXP  32
#define IDIM  1024

#define BM 128
#define BN 128
#define BK 64
#define CAP (T_TOK*2 + NEXP*BM)   // 20480 max padded rows
#define MAX_RT (CAP/BM)           // 160 row tiles max

typedef __attribute__((ext_vector_type(8))) short bh8;   // 8 bf16 (4 VGPR) MFMA A/B frag
typedef __attribute__((ext_vector_type(4))) float f4;    // MFMA C/D frag

// fp32 -> bf16 round-to-nearest-even (bit pattern)
__device__ __forceinline__ unsigned short f2bf(float f) {
    unsigned u = __builtin_bit_cast(unsigned, f);
    u += 0x7FFFu + ((u >> 16) & 1u);
    return (unsigned short)(u >> 16);
}

// XOR swizzle: 128-byte LDS rows, byte ^= (row&7)<<4. Bijective per row,
// uniform bank load for our b128 reads/writes.
__device__ __forceinline__ int swz(int row, int kb) {
    return row * 128 + (kb ^ ((row & 7) << 4));
}

// ---------------- routing ----------------

__device__ __forceinline__ void top2(const float* __restrict__ l,
                                     int& b1, float& v1, int& b2, float& v2) {
    v1 = -1e30f; b1 = 0;
#pragma unroll
    for (int e = 0; e < NEXP; ++e) { float v = l[e]; if (v > v1) { v1 = v; b1 = e; } }
    v2 = -1e30f; b2 = 0;
#pragma unroll
    for (int e = 0; e < NEXP; ++e) { if (e == b1) continue; float v = l[e]; if (v > v2) { v2 = v; b2 = e; } }
}

__global__ void route_count_kernel(const float* __restrict__ logits, int* __restrict__ counts) {
    int t = blockIdx.x * blockDim.x + threadIdx.x;
    if (t >= T_TOK) return;
    int b1, b2; float v1, v2;
    top2(logits + (size_t)t * NEXP, b1, v1, b2, v2);
    atomicAdd(&counts[b1], 1);
    atomicAdd(&counts[b2], 1);
}

__global__ void offsets_kernel(const int* __restrict__ counts, int* __restrict__ offs) {
    if (threadIdx.x == 0) {
        int o = 0;
        for (int e = 0; e < NEXP; ++e) { offs[e] = o; o += (counts[e] + BM - 1) & ~(BM - 1); }
        offs[NEXP] = o;
    }
}

__global__ void route_scatter_kernel(const float* __restrict__ logits,
                                     const float* __restrict__ scale,
                                     const int* __restrict__ offs,
                                     int* __restrict__ cursor,
                                     int* __restrict__ row_tok,
                                     float* __restrict__ row_w) {
    int t = blockIdx.x * blockDim.x + threadIdx.x;
    if (t >= T_TOK) return;
    int b1, b2; float v1, v2;
    top2(logits + (size_t)t * NEXP, b1, v1, b2, v2);
    float e2 = expf(v2 - v1);
    float inv = 1.0f / (1.0f + e2);
    float w1 = scale[b1] * inv;
    float w2 = scale[b2] * e2 * inv;
    int p1 = offs[b1] + atomicAdd(&cursor[b1], 1);
    row_tok[p1] = t; row_w[p1] = w1;
    int p2 = offs[b2] + atomicAdd(&cursor[b2], 1);
    row_tok[p2] = t; row_w[p2] = w2;
}

// ---------------- W transpose-stage (fp32 [k][n] global -> bf16 [n][k] LDS) --------

__device__ __forceinline__ void stage_w(char* dst, const float* __restrict__ src,
                                        long stride, int wn, int wk) {
    float t[32];
#pragma unroll
    for (int kk = 0; kk < 32; ++kk) t[kk] = src[kk * stride];
#pragma unroll
    for (int j = 0; j < 4; ++j) {
        bh8 p;
#pragma unroll
        for (int i = 0; i < 8; ++i) p[i] = (short)f2bf(t[j * 8 + i]);
        *(bh8*)(dst + swz(wn, wk * 64 + j * 16)) = p;
    }
}

// ---------------- GEMM1: act = gelu(X@Wg) * (X@Wu), bf16 out ----------------

__launch_bounds__(256, 2)
__global__ void gemm1_kernel(const float* __restrict__ hs,
                             const float* __restrict__ wg,
                             const float* __restrict__ wu,
                             const int* __restrict__ offs,
                             const int* __restrict__ row_tok,
                             unsigned short* __restrict__ act) {
    __shared__ char lds[48 * 1024];   // Xs 16K | Wg 16K | Wu 16K
    char* Xb = lds;
    char* Gb = lds + 16384;
    char* Ub = lds + 32768;

    int rt = blockIdx.x >> 3;
    int nt = blockIdx.x & 7;
    int total = offs[NEXP];
    if (rt * BM >= total) return;
    int e = 0;
    while (offs[e + 1] <= rt * BM) e++;

    int tid = threadIdx.x;
    int lane = tid & 63;
    int wv = tid >> 6;
    int m0 = wv * 32;

    // X staging mapping: 2 threads per row, 32 floats each
    int sr = tid >> 1;
    int sh = tid & 1;
    int tok = row_tok[rt * BM + sr];
    const float* xsrc = hs + (size_t)(tok < 0 ? 0 : tok) * HDIM + sh * 32;

    // W staging mapping: 1 thread per col, 2 k-halves
    int wn = tid & 127;
    int wk = tid >> 7;
    const float* wgs = wg + (size_t)e * HDIM * IDIM + (size_t)(wk * 32) * IDIM + nt * BN + wn;
    const float* wus = wu + (size_t)e * HDIM * IDIM + (size_t)(wk * 32) * IDIM + nt * BN + wn;

    f4 accG[2][8], accU[2][8];
#pragma unroll
    for (int m = 0; m < 2; ++m)
#pragma unroll
        for (int n = 0; n < 8; ++n) { accG[m][n] = (f4)0.0f; accU[m][n] = (f4)0.0f; }

    for (int kt = 0; kt < HDIM / BK; ++kt) {
        // stage X tile (gather + convert)
        {
            float4 v[8];
#pragma unroll
            for (int j = 0; j < 8; ++j) v[j] = make_float4(0.f, 0.f, 0.f, 0.f);
            if (tok >= 0) {
                const float4* p = (const float4*)(xsrc + kt * BK);
#pragma unroll
                for (int j = 0; j < 8; ++j) v[j] = p[j];
            }
#pragma unroll
            for (int j = 0; j < 4; ++j) {
                float4 a = v[2 * j], b = v[2 * j + 1];
                bh8 p;
                p[0] = (short)f2bf(a.x); p[1] = (short)f2bf(a.y);
                p[2] = (short)f2bf(a.z); p[3] = (short)f2bf(a.w);
                p[4] = (short)f2bf(b.x); p[5] = (short)f2bf(b.y);
                p[6] = (short)f2bf(b.z); p[7] = (short)f2bf(b.w);
                *(bh8*)(Xb + swz(sr, sh * 64 + j * 16)) = p;
            }
        }
        // stage Wg, Wu tiles (transpose + convert)
        stage_w(Gb, wgs + (size_t)kt * BK * IDIM, IDIM, wn, wk);
        stage_w(Ub, wus + (size_t)kt * BK * IDIM, IDIM, wn, wk);
        __syncthreads();

#pragma unroll
        for (int ks = 0; ks < 2; ++ks) {
            int kb = ks * 64 + ((lane >> 4) << 4);
            bh8 a0 = *(const bh8*)(Xb + swz(m0 + (lane & 15), kb));
            bh8 a1 = *(const bh8*)(Xb + swz(m0 + 16 + (lane & 15), kb));
#pragma unroll
            for (int n = 0; n < 8; ++n) {
                int nr = n * 16 + (lane & 15);
                bh8 bg = *(const bh8*)(Gb + swz(nr, kb));
                bh8 bu = *(const bh8*)(Ub + swz(nr, kb));
                accG[0][n] = __builtin_amdgcn_mfma_f32_16x16x32_bf16(a0, bg, accG[0][n], 0, 0, 0);
                accG[1][n] = __builtin_amdgcn_mfma_f32_16x16x32_bf16(a1, bg, accG[1][n], 0, 0, 0);
                accU[0][n] = __builtin_amdgcn_mfma_f32_16x16x32_bf16(a0, bu, accU[0][n], 0, 0, 0);
                accU[1][n] = __builtin_amdgcn_mfma_f32_16x16x32_bf16(a1, bu, accU[1][n], 0, 0, 0);
            }
        }
        __syncthreads();
    }

    // epilogue: gelu(g)*u -> bf16 act
    int col0 = nt * BN + (lane & 15);
#pragma unroll
    for (int m = 0; m < 2; ++m) {
        int rbase = rt * BM + m0 + m * 16 + ((lane >> 4) << 2);
#pragma unroll
        for (int n = 0; n < 8; ++n) {
#pragma unroll
            for (int i = 0; i < 4; ++i) {
                float g = accG[m][n][i], u = accU[m][n][i];
                float gl = 0.5f * g * (1.0f + erff(g * 0.70710678118654752f));
                act[(size_t)(rbase + i) * IDIM + col0 + n * 16] = f2bf(gl * u);
            }
        }
    }
}

// ---------------- GEMM2: out[tok] += w * (act @ Wd) ----------------

__launch_bounds__(256, 2)
__global__ void gemm2_kernel(const unsigned short* __restrict__ act,
                             const float* __restrict__ wd,
                             const int* __restrict__ offs,
                             const int* __restrict__ row_tok,
                             const float* __restrict__ row_w,
                             float* __restrict__ out) {
    __shared__ char lds[32 * 1024];   // As 16K | Wd 16K
    char* Xb = lds;
    char* Db = lds + 16384;

    int rt = blockIdx.x >> 4;
    int nt = blockIdx.x & 15;
    int total = offs[NEXP];
    if (rt * BM >= total) return;
    int e = 0;
    while (offs[e + 1] <= rt * BM) e++;

    int tid = threadIdx.x;
    int lane = tid & 63;
    int wv = tid >> 6;
    int m0 = wv * 32;

    int sr = tid >> 1;
    int sh = tid & 1;
    const unsigned short* asrc = act + (size_t)(rt * BM + sr) * IDIM + sh * 32;

    int wn = tid & 127;
    int wk = tid >> 7;
    const float* wds = wd + (size_t)e * IDIM * HDIM + (size_t)(wk * 32) * HDIM + nt * BN + wn;

    f4 acc[2][8];
#pragma unroll
    for (int m = 0; m < 2; ++m)
#pragma unroll
        for (int n = 0; n < 8; ++n) acc[m][n] = (f4)0.0f;

    for (int kt = 0; kt < IDIM / BK; ++kt) {
        // stage act tile (already bf16, no convert)
        {
            const bh8* p = (const bh8*)(asrc + kt * BK);
#pragma unroll
            for (int j = 0; j < 4; ++j)
                *(bh8*)(Xb + swz(sr, sh * 64 + j * 16)) = p[j];
        }
        stage_w(Db, wds + (size_t)kt * BK * HDIM, HDIM, wn, wk);
        __syncthreads();

#pragma unroll
        for (int ks = 0; ks < 2; ++ks) {
            int kb = ks * 64 + ((lane >> 4) << 4);
            bh8 a0 = *(const bh8*)(Xb + swz(m0 + (lane & 15), kb));
            bh8 a1 = *(const bh8*)(Xb + swz(m0 + 16 + (lane & 15), kb));
#pragma unroll
            for (int n = 0; n < 8; ++n) {
                int nr = n * 16 + (lane & 15);
                bh8 b = *(const bh8*)(Db + swz(nr, kb));
                acc[0][n] = __builtin_amdgcn_mfma_f32_16x16x32_bf16(a0, b, acc[0][n], 0, 0, 0);
                acc[1][n] = __builtin_amdgcn_mfma_f32_16x16x32_bf16(a1, b, acc[1][n], 0, 0, 0);
            }
        }
        __syncthreads();
    }

    // epilogue: scale by routing weight, atomic accumulate into out
    int col0 = nt * BN + (lane & 15);
#pragma unroll
    for (int m = 0; m < 2; ++m) {
        int rbase = rt * BM + m0 + m * 16 + ((lane >> 4) << 2);
#pragma unroll
        for (int i = 0; i < 4; ++i) {
            int r = rbase + i;
            int tok = row_tok[r];
            if (tok < 0) continue;
            float w = row_w[r];
            float* op = out + (size_t)tok * HDIM + col0;
#pragma unroll
            for (int n = 0; n < 8; ++n)
                atomicAdd(op + n * 16, acc[m][n][i] * w);
        }
    }
}

// ---------------- launch ----------------
// ws layout: [0,128) counts | [128,256) cursor | [256,388) offs[33] |
//            [512, 512+CAP*4) row_tok | +CAP*4 row_w | +CAP*4 act bf16[CAP][IDIM]
// required ws: 512 + 20480*8 + 20480*1024*2 = ~42.1 MB

extern "C" void kernel_launch(void* const* d_in, const int* in_sizes, int n_in,
                              void* d_out, int out_size, void* d_ws, size_t ws_size,
                              hipStream_t stream) {
    const float* hs     = (const float*)d_in[0];
    const float* logits = (const float*)d_in[1];
    const float* scale  = (const float*)d_in[2];
    const float* wg     = (const float*)d_in[3];
    const float* wu     = (const float*)d_in[4];
    const float* wd     = (const float*)d_in[5];
    float* out = (float*)d_out;

    char* ws = (char*)d_ws;
    int*   counts  = (int*)ws;
    int*   cursor  = counts + 32;
    int*   offs    = cursor + 32;
    int*   row_tok = (int*)(ws + 512);
    float* row_w   = (float*)(ws + 512 + (size_t)CAP * 4);
    unsigned short* act = (unsigned short*)(ws + 512 + (size_t)CAP * 8);

    hipMemsetAsync(counts, 0, 512, stream);
    hipMemsetAsync(row_tok, 0xFF, (size_t)CAP * 4, stream);
    hipMemsetAsync(out, 0, (size_t)out_size * sizeof(float), stream);

    route_count_kernel<<<T_TOK / 256, 256, 0, stream>>>(logits, counts);
    offsets_kernel<<<1, 64, 0, stream>>>(counts, offs);
    route_scatter_kernel<<<T_TOK / 256, 256, 0, stream>>>(logits, scale, offs, cursor, row_tok, row_w);
    gemm1_kernel<<<MAX_RT * 8, 256, 0, stream>>>(hs, wg, wu, offs, row_tok, act);
    gemm2_kernel<<<MAX_RT * 16, 256, 0, stream>>>(act, wd, offs, row_tok, row_w, out);
}

// Round 2
// 745.934 us; speedup vs baseline: 1.0796x; 1.0796x over previous
//
#include <hip/hip_runtime.h>

#define T_TOK 8192
#define HDIM  2048
#define NEXP  32
#define IDIM  1024

#define BM 128
#define BN 128
#define BK 64
#define CAP (T_TOK*2 + NEXP*BM)   // 20480 max padded rows
#define MAX_RT (CAP/BM)           // 160 row tiles max

typedef __attribute__((ext_vector_type(8))) short bh8;   // 8 bf16 (4 VGPR) MFMA A/B frag
typedef __attribute__((ext_vector_type(4))) float f4;    // MFMA C/D frag

// fp32 -> bf16 round-to-nearest-even (bit pattern)
__device__ __forceinline__ unsigned short f2bf(float f) {
    unsigned u = __builtin_bit_cast(unsigned, f);
    u += 0x7FFFu + ((u >> 16) & 1u);
    return (unsigned short)(u >> 16);
}

// XOR swizzle: 128-byte LDS rows, byte ^= (row&7)<<4.
__device__ __forceinline__ int swz(int row, int kb) {
    return row * 128 + (kb ^ ((row & 7) << 4));
}

// async 16B global->LDS (dest = wave-uniform base + lane*16, source per-lane)
__device__ __forceinline__ void gload16(const void* g, void* l) {
    __builtin_amdgcn_global_load_lds(
        (const __attribute__((address_space(1))) unsigned int*)g,
        (__attribute__((address_space(3))) unsigned int*)l,
        16, 0, 0);
}

// ---------------- routing ----------------

__device__ __forceinline__ void top2(const float* __restrict__ l,
                                     int& b1, float& v1, int& b2, float& v2) {
    v1 = -1e30f; b1 = 0;
#pragma unroll
    for (int e = 0; e < NEXP; ++e) { float v = l[e]; if (v > v1) { v1 = v; b1 = e; } }
    v2 = -1e30f; b2 = 0;
#pragma unroll
    for (int e = 0; e < NEXP; ++e) { if (e == b1) continue; float v = l[e]; if (v > v2) { v2 = v; b2 = e; } }
}

__global__ void route_count_kernel(const float* __restrict__ logits, int* __restrict__ counts) {
    int t = blockIdx.x * blockDim.x + threadIdx.x;
    if (t >= T_TOK) return;
    int b1, b2; float v1, v2;
    top2(logits + (size_t)t * NEXP, b1, v1, b2, v2);
    atomicAdd(&counts[b1], 1);
    atomicAdd(&counts[b2], 1);
}

__global__ void offsets_kernel(const int* __restrict__ counts, int* __restrict__ offs) {
    if (threadIdx.x == 0) {
        int o = 0;
        for (int e = 0; e < NEXP; ++e) { offs[e] = o; o += (counts[e] + BM - 1) & ~(BM - 1); }
        offs[NEXP] = o;
    }
}

__global__ void route_scatter_kernel(const float* __restrict__ logits,
                                     const float* __restrict__ scale,
                                     const int* __restrict__ offs,
                                     int* __restrict__ cursor,
                                     int* __restrict__ row_tok,
                                     float* __restrict__ row_w) {
    int t = blockIdx.x * blockDim.x + threadIdx.x;
    if (t >= T_TOK) return;
    int b1, b2; float v1, v2;
    top2(logits + (size_t)t * NEXP, b1, v1, b2, v2);
    float e2 = expf(v2 - v1);
    float inv = 1.0f / (1.0f + e2);
    float w1 = scale[b1] * inv;
    float w2 = scale[b2] * e2 * inv;
    int p1 = offs[b1] + atomicAdd(&cursor[b1], 1);
    row_tok[p1] = t; row_w[p1] = w1;
    int p2 = offs[b2] + atomicAdd(&cursor[b2], 1);
    row_tok[p2] = t; row_w[p2] = w2;
}

// ================= PATH A: pre-converted bf16 pipeline =================

// hs fp32 -> bf16 streaming convert
__global__ void cvt_hs_kernel(const float* __restrict__ in, unsigned short* __restrict__ out) {
    size_t i = ((size_t)blockIdx.x * 256 + threadIdx.x) * 8;
    float4 a = *(const float4*)(in + i);
    float4 b = *(const float4*)(in + i + 4);
    bh8 v;
    v[0] = (short)f2bf(a.x); v[1] = (short)f2bf(a.y);
    v[2] = (short)f2bf(a.z); v[3] = (short)f2bf(a.w);
    v[4] = (short)f2bf(b.x); v[5] = (short)f2bf(b.y);
    v[6] = (short)f2bf(b.z); v[7] = (short)f2bf(b.w);
    *(bh8*)(out + i) = v;
}

// [E][K][N] fp32 -> [E][N][K] bf16, 64x64 tiles, register-only transpose.
// Reads: per inst 4 rows x 64B full sectors; writes: 16 rows x 64B segments.
__global__ void transpose_cvt_kernel(const float* __restrict__ in,
                                     unsigned short* __restrict__ out,
                                     int K, int N, int tilesN) {
    int bid = blockIdx.x;
    int e = bid >> 9;            // 512 tiles per expert (K*N/4096 = 512 for both shapes)
    int tile = bid & 511;
    int k0 = (tile / tilesN) * 64;
    int n0 = (tile % tilesN) * 64;
    const float* src = in + (size_t)e * K * N;
    unsigned short* dst = out + (size_t)e * K * N;
    int tid = threadIdx.x, l = tid & 63, w = tid >> 6;
    int n = n0 + w * 16 + (l >> 2);
#pragma unroll
    for (int p = 0; p < 2; ++p) {
        int kc = k0 + p * 32 + (l & 3) * 8;
        const float* s = src + (size_t)kc * N + n;
        bh8 v;
#pragma unroll
        for (int j = 0; j < 8; ++j) v[j] = (short)f2bf(s[(size_t)j * N]);
        *(bh8*)(dst + (size_t)n * K + kc) = v;
    }
}

// GEMM1: act = gelu(X@Wg) * (X@Wu), bf16 out (pre-swizzled rows).
// Block: 128 rows x 128 cols(G)+128 cols(U). Waves 2x2 (64r x 64c each).
__launch_bounds__(256, 2)
__global__ void gemm1n_kernel(const unsigned short* __restrict__ hsb,
                              const unsigned short* __restrict__ wgT,
                              const unsigned short* __restrict__ wuT,
                              const int* __restrict__ offs,
                              const int* __restrict__ row_tok,
                              unsigned short* __restrict__ act) {
    __shared__ char lds[49152];
    char* Xb = lds;
    char* Gb = lds + 16384;
    char* Ub = lds + 32768;

    int rt = blockIdx.x >> 3;
    int nt = blockIdx.x & 7;
    int total = offs[NEXP];
    if (rt * BM >= total) return;
    int e = 0;
    while (offs[e + 1] <= rt * BM) e++;

    int tid = threadIdx.x, l = tid & 63, wv = tid >> 6;
    int wm = wv >> 1, wn = wv & 1;

    // per-lane pre-swizzled source chunk within a 128B row
    unsigned srcChunk = ((l & 7) * 16) ^ ((l >> 3) << 4);

    unsigned xoff[4], goff[4], uoff[4];
#pragma unroll
    for (int i = 0; i < 4; ++i) {
        int r = i * 32 + wv * 8 + (l >> 3);
        int tok = row_tok[rt * BM + r];
        if (tok < 0) tok = 0;
        xoff[i] = (unsigned)tok * (HDIM * 2) + srcChunk;
        unsigned wrow = (unsigned)e * IDIM + nt * BN + r;
        goff[i] = wrow * (HDIM * 2) + srcChunk;
        uoff[i] = goff[i];
    }

    f4 accG[4][4], accU[4][4];
#pragma unroll
    for (int mi = 0; mi < 4; ++mi)
#pragma unroll
        for (int ni = 0; ni < 4; ++ni) { accG[mi][ni] = (f4)0.0f; accU[mi][ni] = (f4)0.0f; }

    const char* hsc = (const char*)hsb;
    const char* wgc = (const char*)wgT;
    const char* wuc = (const char*)wuT;

    for (int kt = 0; kt < HDIM / BK; ++kt) {
        unsigned kby = kt * 128;
#pragma unroll
        for (int i = 0; i < 4; ++i) {
            char* dX = Xb + i * 4096 + wv * 1024;
            gload16(hsc + (size_t)xoff[i] + kby, dX);
        }
#pragma unroll
        for (int i = 0; i < 4; ++i) {
            char* dG = Gb + i * 4096 + wv * 1024;
            gload16(wgc + (size_t)goff[i] + kby, dG);
        }
#pragma unroll
        for (int i = 0; i < 4; ++i) {
            char* dU = Ub + i * 4096 + wv * 1024;
            gload16(wuc + (size_t)uoff[i] + kby, dU);
        }
        __syncthreads();

#pragma unroll
        for (int ks = 0; ks < 2; ++ks) {
            int kb = ks * 64 + ((l >> 4) << 4);
            bh8 a[4], g[4], u[4];
#pragma unroll
            for (int mi = 0; mi < 4; ++mi)
                a[mi] = *(const bh8*)(Xb + swz(wm * 64 + mi * 16 + (l & 15), kb));
#pragma unroll
            for (int ni = 0; ni < 4; ++ni) {
                int nr = wn * 64 + ni * 16 + (l & 15);
                g[ni] = *(const bh8*)(Gb + swz(nr, kb));
                u[ni] = *(const bh8*)(Ub + swz(nr, kb));
            }
#pragma unroll
            for (int mi = 0; mi < 4; ++mi)
#pragma unroll
                for (int ni = 0; ni < 4; ++ni) {
                    accG[mi][ni] = __builtin_amdgcn_mfma_f32_16x16x32_bf16(a[mi], g[ni], accG[mi][ni], 0, 0, 0);
                    accU[mi][ni] = __builtin_amdgcn_mfma_f32_16x16x32_bf16(a[mi], u[ni], accU[mi][ni], 0, 0, 0);
                }
        }
        __syncthreads();
    }

    // epilogue: gelu(g)*u -> bf16 act, pre-swizzled byte layout
    char* actc = (char*)act;
#pragma unroll
    for (int mi = 0; mi < 4; ++mi) {
#pragma unroll
        for (int i = 0; i < 4; ++i) {
            int r = rt * BM + wm * 64 + mi * 16 + ((l >> 4) << 2) + i;
            size_t rowbase = (size_t)r * (IDIM * 2);
            int rs = (r & 7) << 4;
#pragma unroll
            for (int ni = 0; ni < 4; ++ni) {
                int col = nt * BN + wn * 64 + ni * 16 + (l & 15);
                float gv = accG[mi][ni][i], uv = accU[mi][ni][i];
                float gl = 0.5f * gv * (1.0f + erff(gv * 0.70710678118654752f));
                *(unsigned short*)(actc + rowbase + ((col * 2) ^ rs)) = f2bf(gl * uv);
            }
        }
    }
}

// GEMM2: out[tok] += w * (act @ WdT^T). Block 128 rows x 256 cols, waves 2x2 (64x128).
__launch_bounds__(256, 2)
__global__ void gemm2n_kernel(const unsigned short* __restrict__ act,
                              const unsigned short* __restrict__ wdT,
                              const int* __restrict__ offs,
                              const int* __restrict__ row_tok,
                              const float* __restrict__ row_w,
                              float* __restrict__ out) {
    __shared__ char lds[49152];
    char* Xb = lds;          // 128 x 128B
    char* Db = lds + 16384;  // 256 x 128B

    int rt = blockIdx.x >> 3;
    int nt = blockIdx.x & 7;   // 2048 / 256
    int total = offs[NEXP];
    if (rt * BM >= total) return;
    int e = 0;
    while (offs[e + 1] <= rt * BM) e++;

    int tid = threadIdx.x, l = tid & 63, wv = tid >> 6;
    int wm = wv >> 1, wn = wv & 1;

    unsigned srcChunk = ((l & 7) * 16) ^ ((l >> 3) << 4);

    unsigned aoff[4];
#pragma unroll
    for (int i = 0; i < 4; ++i) {
        int r = i * 32 + wv * 8 + (l >> 3);
        aoff[i] = (unsigned)(rt * BM + r) * (IDIM * 2) + (l & 7) * 16;  // act pre-swizzled: linear source
    }
    unsigned doff[8];
#pragma unroll
    for (int i = 0; i < 8; ++i) {
        int r = i * 32 + wv * 8 + (l >> 3);
        doff[i] = ((unsigned)e * HDIM + nt * 256 + r) * (IDIM * 2) + srcChunk;
    }

    f4 acc[4][8];
#pragma unroll
    for (int mi = 0; mi < 4; ++mi)
#pragma unroll
        for (int ni = 0; ni < 8; ++ni) acc[mi][ni] = (f4)0.0f;

    const char* actc = (const char*)act;
    const char* wdc = (const char*)wdT;

    for (int kt = 0; kt < IDIM / BK; ++kt) {
        unsigned kby = kt * 128;
#pragma unroll
        for (int i = 0; i < 4; ++i) {
            char* dX = Xb + i * 4096 + wv * 1024;
            gload16(actc + (size_t)aoff[i] + kby, dX);
        }
#pragma unroll
        for (int i = 0; i < 8; ++i) {
            char* dD = Db + i * 4096 + wv * 1024;
            gload16(wdc + (size_t)doff[i] + kby, dD);
        }
        __syncthreads();

#pragma unroll
        for (int ks = 0; ks < 2; ++ks) {
            int kb = ks * 64 + ((l >> 4) << 4);
            bh8 a[4], b[8];
#pragma unroll
            for (int mi = 0; mi < 4; ++mi)
                a[mi] = *(const bh8*)(Xb + swz(wm * 64 + mi * 16 + (l & 15), kb));
#pragma unroll
            for (int ni = 0; ni < 8; ++ni)
                b[ni] = *(const bh8*)(Db + swz(wn * 128 + ni * 16 + (l & 15), kb));
#pragma unroll
            for (int mi = 0; mi < 4; ++mi)
#pragma unroll
                for (int ni = 0; ni < 8; ++ni)
                    acc[mi][ni] = __builtin_amdgcn_mfma_f32_16x16x32_bf16(a[mi], b[ni], acc[mi][ni], 0, 0, 0);
        }
        __syncthreads();
    }

    // epilogue: scale by routing weight, atomic accumulate
#pragma unroll
    for (int mi = 0; mi < 4; ++mi) {
#pragma unroll
        for (int i = 0; i < 4; ++i) {
            int r = rt * BM + wm * 64 + mi * 16 + ((l >> 4) << 2) + i;
            int tok = row_tok[r];
            if (tok < 0) continue;
            float w = row_w[r];
            float* op = out + (size_t)tok * HDIM + nt * 256 + wn * 128 + (l & 15);
#pragma unroll
            for (int ni = 0; ni < 8; ++ni)
                atomicAdd(op + ni * 16, acc[mi][ni][i] * w);
        }
    }
}

// ================= PATH B: round-1 fallback (small workspace) =================

__device__ __forceinline__ void stage_w(char* dst, const float* __restrict__ src,
                                        long stride, int wn, int wk) {
    float t[32];
#pragma unroll
    for (int kk = 0; kk < 32; ++kk) t[kk] = src[kk * stride];
#pragma unroll
    for (int j = 0; j < 4; ++j) {
        bh8 p;
#pragma unroll
        for (int i = 0; i < 8; ++i) p[i] = (short)f2bf(t[j * 8 + i]);
        *(bh8*)(dst + swz(wn, wk * 64 + j * 16)) = p;
    }
}

__launch_bounds__(256, 2)
__global__ void gemm1_kernel(const float* __restrict__ hs,
                             const float* __restrict__ wg,
                             const float* __restrict__ wu,
                             const int* __restrict__ offs,
                             const int* __restrict__ row_tok,
                             unsigned short* __restrict__ act) {
    __shared__ char lds[48 * 1024];
    char* Xb = lds;
    char* Gb = lds + 16384;
    char* Ub = lds + 32768;

    int rt = blockIdx.x >> 3;
    int nt = blockIdx.x & 7;
    int total = offs[NEXP];
    if (rt * BM >= total) return;
    int e = 0;
    while (offs[e + 1] <= rt * BM) e++;

    int tid = threadIdx.x;
    int lane = tid & 63;
    int wv = tid >> 6;
    int m0 = wv * 32;

    int sr = tid >> 1;
    int sh = tid & 1;
    int tok = row_tok[rt * BM + sr];
    const float* xsrc = hs + (size_t)(tok < 0 ? 0 : tok) * HDIM + sh * 32;

    int wn = tid & 127;
    int wk = tid >> 7;
    const float* wgs = wg + (size_t)e * HDIM * IDIM + (size_t)(wk * 32) * IDIM + nt * BN + wn;
    const float* wus = wu + (size_t)e * HDIM * IDIM + (size_t)(wk * 32) * IDIM + nt * BN + wn;

    f4 accG[2][8], accU[2][8];
#pragma unroll
    for (int m = 0; m < 2; ++m)
#pragma unroll
        for (int n = 0; n < 8; ++n) { accG[m][n] = (f4)0.0f; accU[m][n] = (f4)0.0f; }

    for (int kt = 0; kt < HDIM / BK; ++kt) {
        {
            float4 v[8];
#pragma unroll
            for (int j = 0; j < 8; ++j) v[j] = make_float4(0.f, 0.f, 0.f, 0.f);
            if (tok >= 0) {
                const float4* p = (const float4*)(xsrc + kt * BK);
#pragma unroll
                for (int j = 0; j < 8; ++j) v[j] = p[j];
            }
#pragma unroll
            for (int j = 0; j < 4; ++j) {
                float4 a = v[2 * j], b = v[2 * j + 1];
                bh8 p;
                p[0] = (short)f2bf(a.x); p[1] = (short)f2bf(a.y);
                p[2] = (short)f2bf(a.z); p[3] = (short)f2bf(a.w);
                p[4] = (short)f2bf(b.x); p[5] = (short)f2bf(b.y);
                p[6] = (short)f2bf(b.z); p[7] = (short)f2bf(b.w);
                *(bh8*)(Xb + swz(sr, sh * 64 + j * 16)) = p;
            }
        }
        stage_w(Gb, wgs + (size_t)kt * BK * IDIM, IDIM, wn, wk);
        stage_w(Ub, wus + (size_t)kt * BK * IDIM, IDIM, wn, wk);
        __syncthreads();

#pragma unroll
        for (int ks = 0; ks < 2; ++ks) {
            int kb = ks * 64 + ((lane >> 4) << 4);
            bh8 a0 = *(const bh8*)(Xb + swz(m0 + (lane & 15), kb));
            bh8 a1 = *(const bh8*)(Xb + swz(m0 + 16 + (lane & 15), kb));
#pragma unroll
            for (int n = 0; n < 8; ++n) {
                int nr = n * 16 + (lane & 15);
                bh8 bg = *(const bh8*)(Gb + swz(nr, kb));
                bh8 bu = *(const bh8*)(Ub + swz(nr, kb));
                accG[0][n] = __builtin_amdgcn_mfma_f32_16x16x32_bf16(a0, bg, accG[0][n], 0, 0, 0);
                accG[1][n] = __builtin_amdgcn_mfma_f32_16x16x32_bf16(a1, bg, accG[1][n], 0, 0, 0);
                accU[0][n] = __builtin_amdgcn_mfma_f32_16x16x32_bf16(a0, bu, accU[0][n], 0, 0, 0);
                accU[1][n] = __builtin_amdgcn_mfma_f32_16x16x32_bf16(a1, bu, accU[1][n], 0, 0, 0);
            }
        }
        __syncthreads();
    }

    int col0 = nt * BN + (lane & 15);
#pragma unroll
    for (int m = 0; m < 2; ++m) {
        int rbase = rt * BM + m0 + m * 16 + ((lane >> 4) << 2);
#pragma unroll
        for (int n = 0; n < 8; ++n) {
#pragma unroll
            for (int i = 0; i < 4; ++i) {
                float g = accG[m][n][i], u = accU[m][n][i];
                float gl = 0.5f * g * (1.0f + erff(g * 0.70710678118654752f));
                act[(size_t)(rbase + i) * IDIM + col0 + n * 16] = f2bf(gl * u);
            }
        }
    }
}

__launch_bounds__(256, 2)
__global__ void gemm2_kernel(const unsigned short* __restrict__ act,
                             const float* __restrict__ wd,
                             const int* __restrict__ offs,
                             const int* __restrict__ row_tok,
                             const float* __restrict__ row_w,
                             float* __restrict__ out) {
    __shared__ char lds[32 * 1024];
    char* Xb = lds;
    char* Db = lds + 16384;

    int rt = blockIdx.x >> 4;
    int nt = blockIdx.x & 15;
    int total = offs[NEXP];
    if (rt * BM >= total) return;
    int e = 0;
    while (offs[e + 1] <= rt * BM) e++;

    int tid = threadIdx.x;
    int lane = tid & 63;
    int wv = tid >> 6;
    int m0 = wv * 32;

    int sr = tid >> 1;
    int sh = tid & 1;
    const unsigned short* asrc = act + (size_t)(rt * BM + sr) * IDIM + sh * 32;

    int wn = tid & 127;
    int wk = tid >> 7;
    const float* wds = wd + (size_t)e * IDIM * HDIM + (size_t)(wk * 32) * HDIM + nt * BN + wn;

    f4 acc[2][8];
#pragma unroll
    for (int m = 0; m < 2; ++m)
#pragma unroll
        for (int n = 0; n < 8; ++n) acc[m][n] = (f4)0.0f;

    for (int kt = 0; kt < IDIM / BK; ++kt) {
        {
            const bh8* p = (const bh8*)(asrc + kt * BK);
#pragma unroll
            for (int j = 0; j < 4; ++j)
                *(bh8*)(Xb + swz(sr, sh * 64 + j * 16)) = p[j];
        }
        stage_w(Db, wds + (size_t)kt * BK * HDIM, HDIM, wn, wk);
        __syncthreads();

#pragma unroll
        for (int ks = 0; ks < 2; ++ks) {
            int kb = ks * 64 + ((lane >> 4) << 4);
            bh8 a0 = *(const bh8*)(Xb + swz(m0 + (lane & 15), kb));
            bh8 a1 = *(const bh8*)(Xb + swz(m0 + 16 + (lane & 15), kb));
#pragma unroll
            for (int n = 0; n < 8; ++n) {
                int nr = n * 16 + (lane & 15);
                bh8 b = *(const bh8*)(Db + swz(nr, kb));
                acc[0][n] = __builtin_amdgcn_mfma_f32_16x16x32_bf16(a0, b, acc[0][n], 0, 0, 0);
                acc[1][n] = __builtin_amdgcn_mfma_f32_16x16x32_bf16(a1, b, acc[1][n], 0, 0, 0);
            }
        }
        __syncthreads();
    }

    int col0 = nt * BN + (lane & 15);
#pragma unroll
    for (int m = 0; m < 2; ++m) {
        int rbase = rt * BM + m0 + m * 16 + ((lane >> 4) << 2);
#pragma unroll
        for (int i = 0; i < 4; ++i) {
            int r = rbase + i;
            int tok = row_tok[r];
            if (tok < 0) continue;
            float w = row_w[r];
            float* op = out + (size_t)tok * HDIM + col0;
#pragma unroll
            for (int n = 0; n < 8; ++n)
                atomicAdd(op + n * 16, acc[m][n][i] * w);
        }
    }
}

// ---------------- launch ----------------
// Path A ws layout:
//   [0,512): counts(128) | cursor(128) | offs(132)
//   512:                    row_tok  CAP*4
//   512+CAP*4:               row_w    CAP*4
//   512+CAP*8:               act      CAP*IDIM*2        (41.9 MB)
//   +:                       hs_bf16  T*H*2             (33.6 MB)
//   +:                       wgT      E*I*H*2           (134.2 MB)  [reused as wdT]
//   +:                       wuT      E*I*H*2           (134.2 MB)
//   total ~344.1 MB

extern "C" void kernel_launch(void* const* d_in, const int* in_sizes, int n_in,
                              void* d_out, int out_size, void* d_ws, size_t ws_size,
                              hipStream_t stream) {
    const float* hs     = (const float*)d_in[0];
    const float* logits = (const float*)d_in[1];
    const float* scale  = (const float*)d_in[2];
    const float* wg     = (const float*)d_in[3];
    const float* wu     = (const float*)d_in[4];
    const float* wd     = (const float*)d_in[5];
    float* out = (float*)d_out;

    char* ws = (char*)d_ws;
    int*   counts  = (int*)ws;
    int*   cursor  = counts + 32;
    int*   offs    = cursor + 32;
    int*   row_tok = (int*)(ws + 512);
    float* row_w   = (float*)(ws + 512 + (size_t)CAP * 4);
    unsigned short* act = (unsigned short*)(ws + 512 + (size_t)CAP * 8);

    size_t actB  = (size_t)CAP * IDIM * 2;
    size_t hsB   = (size_t)T_TOK * HDIM * 2;
    size_t wTB   = (size_t)NEXP * IDIM * HDIM * 2;
    size_t baseA = 512 + (size_t)CAP * 8;
    size_t needA = baseA + actB + hsB + 2 * wTB;

    hipMemsetAsync(counts, 0, 512, stream);
    hipMemsetAsync(row_tok, 0xFF, (size_t)CAP * 4, stream);
    hipMemsetAsync(out, 0, (size_t)out_size * sizeof(float), stream);

    route_count_kernel<<<T_TOK / 256, 256, 0, stream>>>(logits, counts);
    offsets_kernel<<<1, 64, 0, stream>>>(counts, offs);
    route_scatter_kernel<<<T_TOK / 256, 256, 0, stream>>>(logits, scale, offs, cursor, row_tok, row_w);

    if (ws_size >= needA) {
        unsigned short* hsb = (unsigned short*)(ws + baseA + actB);
        unsigned short* wgT = (unsigned short*)(ws + baseA + actB + hsB);
        unsigned short* wuT = (unsigned short*)(ws + baseA + actB + hsB + wTB);
        unsigned short* wdT = wgT;  // reused after gemm1

        cvt_hs_kernel<<<(T_TOK * HDIM) / (256 * 8), 256, 0, stream>>>(hs, hsb);
        transpose_cvt_kernel<<<NEXP * 512, 256, 0, stream>>>(wg, wgT, HDIM, IDIM, 16);
        transpose_cvt_kernel<<<NEXP * 512, 256, 0, stream>>>(wu, wuT, HDIM, IDIM, 16);
        gemm1n_kernel<<<MAX_RT * 8, 256, 0, stream>>>(hsb, wgT, wuT, offs, row_tok, act);
        transpose_cvt_kernel<<<NEXP * 512, 256, 0, stream>>>(wd, wdT, IDIM, HDIM, 32);
        gemm2n_kernel<<<MAX_RT * 8, 256, 0, stream>>>(act, wdT, offs, row_tok, row_w, out);
    } else {
        gemm1_kernel<<<MAX_RT * 8, 256, 0, stream>>>(hs, wg, wu, offs, row_tok, act);
        gemm2_kernel<<<MAX_RT * 16, 256, 0, stream>>>(act, wd, offs, row_tok, row_w, out);
    }
}